// Round 1
// baseline (12402.071 us; speedup 1.0000x reference)
//
#include <hip/hip_runtime.h>
#include <stdint.h>

#define T_STEPS 512
#define BATCH   128
#define HID     512
#define KTOT    1024

typedef __attribute__((ext_vector_type(8))) short          bf16x8;
typedef __attribute__((ext_vector_type(8))) unsigned short u16x8;
typedef __attribute__((ext_vector_type(4))) float          f32x4;

__device__ inline unsigned short f2bf(float f) {
    union { float f; unsigned u; } x; x.f = f;
    unsigned r = x.u + 0x7FFFu + ((x.u >> 16) & 1u);   // RNE
    return (unsigned short)(r >> 16);
}

__device__ inline float sigmoidf_(float x) { return 1.f / (1.f + __expf(-x)); }
__device__ inline float tanhf_(float x)    { float e = __expf(2.f * x); return 1.f - 2.f / (e + 1.f); }

// one-shot fp32 -> bf16 cast of the input sequence (T*B*HID elems, /8 per thread)
__global__ void cast_x_kernel(const float* __restrict__ x, unsigned short* __restrict__ y, int n) {
    int i = (blockIdx.x * blockDim.x + threadIdx.x) * 8;
    if (i >= n) return;
    float4 a = *(const float4*)(x + i);
    float4 b = *(const float4*)(x + i + 4);
    u16x8 v;
    v[0] = f2bf(a.x); v[1] = f2bf(a.y); v[2] = f2bf(a.z); v[3] = f2bf(a.w);
    v[4] = f2bf(b.x); v[5] = f2bf(b.y); v[6] = f2bf(b.z); v[7] = f2bf(b.w);
    *(u16x8*)(y + i) = v;
}

// Persistent LSTM kernel.
// grid = 128 blocks (8 batch-groups x 16 col-groups), block = 512 threads (8 waves).
// wave w: gate = w&3 (f,i,g,o), unit-half = w>>2; owns 16 hidden units, M=16 batch rows.
// W slice lives in 128 VGPRs/lane as bf16 MFMA B-fragments; weights read from HBM once.
__global__ __launch_bounds__(512, 2) void lstm_kernel(
    const float* __restrict__ xf,
    const unsigned short* __restrict__ xbf,
    const float* __restrict__ Wf, const float* __restrict__ bfv,
    const float* __restrict__ Wi, const float* __restrict__ biv,
    const float* __restrict__ Wg, const float* __restrict__ bgv,
    const float* __restrict__ Wo, const float* __restrict__ bov,
    float* __restrict__ out,
    unsigned int* __restrict__ cnt,
    unsigned short* __restrict__ hbuf,
    int use_xbf)
{
    // LDS: combined [16 rows][1024 bf16] padded to 1032 shorts (2064B rows: 16B-aligned,
    // bank stride 4 dwords/row -> worst 2-way aliasing = free). Gates/c padded +1 col.
    __shared__ __align__(16) unsigned short comb[16][1032];
    __shared__ float gatesl[4][16][33];
    __shared__ float cl[16][33];

    const int tid  = threadIdx.x;
    const int bgc  = blockIdx.x >> 4;    // batch group 0..7  (rows bgc*16..+16)
    const int cg   = blockIdx.x & 15;    // col group 0..15   (units cg*32..+32)
    const int w    = tid >> 6;           // wave 0..7
    const int lane = tid & 63;
    const int gate = w & 3;              // 0=f 1=i 2=g 3=o
    const int uh   = w >> 2;             // unit half 0..1
    const int n    = lane & 15;
    const int quad = lane >> 4;
    const int unit = cg * 32 + uh * 16 + n;   // global hidden unit this lane's B-col

    const float* Wp = (gate == 0) ? Wf : (gate == 1) ? Wi : (gate == 2) ? Wg : Wo;
    const float* bp = (gate == 0) ? bfv : (gate == 1) ? biv : (gate == 2) ? bgv : bov;
    const float bias = bp[unit];

    // ---- preload W slice into registers as bf16 B-fragments (once) ----
    bf16x8 wfr[32];
    const float* wrow = Wp + (size_t)unit * KTOT;
#pragma unroll
    for (int kk = 0; kk < 32; ++kk) {
        const float4* p = (const float4*)(wrow + kk * 32 + quad * 8);
        float4 a = p[0], b = p[1];
        u16x8 v;
        v[0] = f2bf(a.x); v[1] = f2bf(a.y); v[2] = f2bf(a.z); v[3] = f2bf(a.w);
        v[4] = f2bf(b.x); v[5] = f2bf(b.y); v[6] = f2bf(b.z); v[7] = f2bf(b.w);
        wfr[kk] = (bf16x8)v;
    }

    // zero c state
    {
        const int b = tid >> 5, u = tid & 31;
        cl[b][u] = 0.f;
    }

    const int srow = tid >> 5;   // staging row 0..15
    const int scol = tid & 31;   // 32 threads/row, 16 bf16 (32B) each

    for (int t = 0; t < T_STEPS; ++t) {
        // ---- stage x-part (k = 0..511) into LDS ----
        if (use_xbf) {
            const uint4* src = (const uint4*)(xbf + ((size_t)(t * BATCH + bgc * 16 + srow)) * HID + scol * 16);
            uint4 v0 = src[0], v1 = src[1];
            *(uint4*)&comb[srow][scol * 16]     = v0;
            *(uint4*)&comb[srow][scol * 16 + 8] = v1;
        } else {
            const float4* src = (const float4*)(xf + ((size_t)(t * BATCH + bgc * 16 + srow)) * HID + scol * 16);
            float4 a0 = src[0], a1 = src[1], a2 = src[2], a3 = src[3];
            u16x8 v;
            v[0] = f2bf(a0.x); v[1] = f2bf(a0.y); v[2] = f2bf(a0.z); v[3] = f2bf(a0.w);
            v[4] = f2bf(a1.x); v[5] = f2bf(a1.y); v[6] = f2bf(a1.z); v[7] = f2bf(a1.w);
            *(u16x8*)&comb[srow][scol * 16] = v;
            u16x8 v2;
            v2[0] = f2bf(a2.x); v2[1] = f2bf(a2.y); v2[2] = f2bf(a2.z); v2[3] = f2bf(a2.w);
            v2[4] = f2bf(a3.x); v2[5] = f2bf(a3.y); v2[6] = f2bf(a3.z); v2[7] = f2bf(a3.w);
            *(u16x8*)&comb[srow][scol * 16 + 8] = v2;
        }
        __syncthreads();

        // ---- x-half MFMAs (no dependence on h_{t-1}; hides flag latency) ----
        f32x4 acc0 = {0.f, 0.f, 0.f, 0.f};
#pragma unroll
        for (int kk = 0; kk < 16; ++kk) {
            bf16x8 a = *(const bf16x8*)&comb[n][kk * 32 + quad * 8];
            acc0 = __builtin_amdgcn_mfma_f32_16x16x32_bf16(a, wfr[kk], acc0, 0, 0, 0);
        }

        // ---- wait for h_{t-1} from the 16 col-WGs of this batch group, stage it ----
        if (t > 0) {
            if (tid == 0) {
                const unsigned int* cp = cnt + (size_t)(t - 1) * 8 + bgc;
                while (__hip_atomic_load(cp, __ATOMIC_ACQUIRE, __HIP_MEMORY_SCOPE_AGENT) < 16u) {
                    __builtin_amdgcn_s_sleep(1);
                }
            }
            __syncthreads();
            const uint4* src = (const uint4*)(hbuf + ((size_t)((t & 1) ^ 1)) * BATCH * HID
                                              + (size_t)(bgc * 16 + srow) * HID + scol * 16);
            uint4 v0 = src[0], v1 = src[1];
            *(uint4*)&comb[srow][512 + scol * 16]     = v0;
            *(uint4*)&comb[srow][512 + scol * 16 + 8] = v1;
        } else {
            uint4 z = {0u, 0u, 0u, 0u};
            *(uint4*)&comb[srow][512 + scol * 16]     = z;
            *(uint4*)&comb[srow][512 + scol * 16 + 8] = z;
        }
        __syncthreads();

        // ---- h-half MFMAs ----
        f32x4 acc1 = {0.f, 0.f, 0.f, 0.f};
#pragma unroll
        for (int kk = 16; kk < 32; ++kk) {
            bf16x8 a = *(const bf16x8*)&comb[n][kk * 32 + quad * 8];
            acc1 = __builtin_amdgcn_mfma_f32_16x16x32_bf16(a, wfr[kk], acc1, 0, 0, 0);
        }

        // ---- activations -> LDS gate exchange ----
#pragma unroll
        for (int r = 0; r < 4; ++r) {
            float v = acc0[r] + acc1[r] + bias;
            v = (gate == 2) ? tanhf_(v) : sigmoidf_(v);
            gatesl[gate][quad * 4 + r][uh * 16 + n] = v;
        }
        __syncthreads();

        // ---- LSTM cell elementwise; write outputs + h broadcast ----
        {
            const int b = tid >> 5, u = tid & 31;
            float fv = gatesl[0][b][u], iv = gatesl[1][b][u];
            float gv = gatesl[2][b][u], ov = gatesl[3][b][u];
            float cn = fv * cl[b][u] + iv * gv;
            cl[b][u] = cn;
            float hv = ov * tanhf_(cn);
            const int bglob = bgc * 16 + b;
            const int uglob = cg * 32 + u;
            out[(size_t)t * BATCH * HID + (size_t)bglob * HID + uglob] = hv;
            hbuf[(size_t)(t & 1) * BATCH * HID + (size_t)bglob * HID + uglob] = f2bf(hv);
            if (t == T_STEPS - 1) {
                out[(size_t)T_STEPS * BATCH * HID + (size_t)bglob * HID + uglob] = hv;                 // hx
                out[(size_t)T_STEPS * BATCH * HID + BATCH * HID + (size_t)bglob * HID + uglob] = cn;   // cx
            }
        }

        // ---- publish h_t (device-scope release) ----
        __threadfence();
        __syncthreads();
        if (tid == 0) {
            atomicAdd(cnt + (size_t)t * 8 + bgc, 1u);
        }
    }
}

extern "C" void kernel_launch(void* const* d_in, const int* in_sizes, int n_in,
                              void* d_out, int out_size, void* d_ws, size_t ws_size,
                              hipStream_t stream) {
    (void)in_sizes; (void)n_in; (void)out_size;
    const float* x   = (const float*)d_in[0];
    const float* Wf  = (const float*)d_in[1];
    const float* bfv = (const float*)d_in[2];
    const float* Wi  = (const float*)d_in[3];
    const float* biv = (const float*)d_in[4];
    const float* Wg  = (const float*)d_in[5];
    const float* bgv = (const float*)d_in[6];
    const float* Wo  = (const float*)d_in[7];
    const float* bov = (const float*)d_in[8];
    float* out = (float*)d_out;

    unsigned char* ws = (unsigned char*)d_ws;
    unsigned int*   cnt  = (unsigned int*)ws;                       // 512*8*4 = 16 KB
    unsigned short* hbuf = (unsigned short*)(ws + 65536);           // 2*128*512*2 = 256 KB
    unsigned short* xbf  = (unsigned short*)(ws + 65536 + 262144);  // 67 MB (optional)

    size_t need = 65536 + 262144 + (size_t)T_STEPS * BATCH * HID * 2;
    int use_xbf = (ws_size >= need) ? 1 : 0;

    hipMemsetAsync(cnt, 0, T_STEPS * 8 * sizeof(unsigned int), stream);
    if (use_xbf) {
        int nelem = T_STEPS * BATCH * HID;                          // 33.5M, /8 per thread
        cast_x_kernel<<<nelem / (256 * 8), 256, 0, stream>>>(x, xbf, nelem);
    }
    lstm_kernel<<<dim3(128), dim3(512), 0, stream>>>(
        x, xbf, Wf, bfv, Wi, biv, Wg, bgv, Wo, bov, out, cnt, hbuf, use_xbf);
}

// Round 2
// 1970.697 us; speedup vs baseline: 6.2932x; 6.2932x over previous
//
#include <hip/hip_runtime.h>
#include <stdint.h>

#define T_STEPS 512
#define BATCH   128
#define HID     512
#define KTOT    1024

typedef __attribute__((ext_vector_type(8))) short          bf16x8;
typedef __attribute__((ext_vector_type(8))) unsigned short u16x8;
typedef __attribute__((ext_vector_type(4))) float          f32x4;

__device__ inline unsigned short f2bf(float f) {
    union { float f; unsigned u; } x; x.f = f;
    unsigned r = x.u + 0x7FFFu + ((x.u >> 16) & 1u);   // RNE
    return (unsigned short)(r >> 16);
}

__device__ inline float sigmoidf_(float x) { return 1.f / (1.f + __expf(-x)); }
__device__ inline float tanhf_(float x)    { float e = __expf(2.f * x); return 1.f - 2.f / (e + 1.f); }

// one-shot fp32 -> bf16 cast of the input sequence
__global__ void cast_x_kernel(const float* __restrict__ x, unsigned short* __restrict__ y, int n) {
    int i = (blockIdx.x * blockDim.x + threadIdx.x) * 8;
    if (i >= n) return;
    float4 a = *(const float4*)(x + i);
    float4 b = *(const float4*)(x + i + 4);
    u16x8 v;
    v[0] = f2bf(a.x); v[1] = f2bf(a.y); v[2] = f2bf(a.z); v[3] = f2bf(a.w);
    v[4] = f2bf(b.x); v[5] = f2bf(b.y); v[6] = f2bf(b.z); v[7] = f2bf(b.w);
    *(u16x8*)(y + i) = v;
}

// Persistent LSTM. grid = 128 WGs (8 batch-groups x 16 col-groups), block = 512.
// Cross-WG sync: relaxed agent-scope atomics ONLY (sc1 bypass -> LLC-coherent).
// NO __threadfence (buffer_wbl2), NO acquire polls (buffer_inv), NO contended RMW:
// producer: bypass data stores -> s_waitcnt(0) -> one relaxed flag store.
__global__ __launch_bounds__(512, 2) void lstm_kernel(
    const float* __restrict__ xf,
    const unsigned short* __restrict__ xbf,
    const float* __restrict__ Wf, const float* __restrict__ bfv,
    const float* __restrict__ Wi, const float* __restrict__ biv,
    const float* __restrict__ Wg, const float* __restrict__ bgv,
    const float* __restrict__ Wo, const float* __restrict__ bov,
    float* __restrict__ out,
    unsigned int* __restrict__ flags,      // [T][8][16] one dword per producer WG
    unsigned short* __restrict__ hbuf,     // [2][128][512] bf16, coherent-access only
    int use_xbf)
{
    // comb rows padded to 1048 shorts (2096 B): n-stride = 524 dwords = 12 banks mod 32
    // -> lanes n and n+8 alias 2-way only (free); 16B-aligned for b128.
    __shared__ __align__(16) unsigned short comb[16][1048];
    __shared__ float gatesl[4][16][33];
    __shared__ float cl[16][33];

    const int tid  = threadIdx.x;
    const int bgc  = blockIdx.x >> 4;    // batch group 0..7
    const int cg   = blockIdx.x & 15;    // col group 0..15
    const int w    = tid >> 6;
    const int lane = tid & 63;
    const int gate = w & 3;              // 0=f 1=i 2=g 3=o
    const int uh   = w >> 2;
    const int n    = lane & 15;
    const int quad = lane >> 4;
    const int unit = cg * 32 + uh * 16 + n;

    const float* Wp = (gate == 0) ? Wf : (gate == 1) ? Wi : (gate == 2) ? Wg : Wo;
    const float* bp = (gate == 0) ? bfv : (gate == 1) ? biv : (gate == 2) ? bgv : bov;
    const float bias = bp[unit];

    // ---- preload W slice into registers as bf16 B-fragments (once) ----
    bf16x8 wfr[32];
    const float* wrow = Wp + (size_t)unit * KTOT;
#pragma unroll
    for (int kk = 0; kk < 32; ++kk) {
        const float4* p = (const float4*)(wrow + kk * 32 + quad * 8);
        float4 a = p[0], b = p[1];
        u16x8 v;
        v[0] = f2bf(a.x); v[1] = f2bf(a.y); v[2] = f2bf(a.z); v[3] = f2bf(a.w);
        v[4] = f2bf(b.x); v[5] = f2bf(b.y); v[6] = f2bf(b.z); v[7] = f2bf(b.w);
        wfr[kk] = (bf16x8)v;
    }

    {
        const int b = tid >> 5, u = tid & 31;
        cl[b][u] = 0.f;
    }

    const int srow = tid >> 5;   // staging row 0..15
    const int scol = tid & 31;   // 16 shorts (32B) per thread per row

    for (int t = 0; t < T_STEPS; ++t) {
        // ---- stage x_t (k = 0..511) into LDS ----
        if (use_xbf) {
            const uint4* src = (const uint4*)(xbf + ((size_t)(t * BATCH + bgc * 16 + srow)) * HID + scol * 16);
            uint4 v0 = src[0], v1 = src[1];
            *(uint4*)&comb[srow][scol * 16]     = v0;
            *(uint4*)&comb[srow][scol * 16 + 8] = v1;
        } else {
            const float4* src = (const float4*)(xf + ((size_t)(t * BATCH + bgc * 16 + srow)) * HID + scol * 16);
            float4 a0 = src[0], a1 = src[1], a2 = src[2], a3 = src[3];
            u16x8 v;
            v[0] = f2bf(a0.x); v[1] = f2bf(a0.y); v[2] = f2bf(a0.z); v[3] = f2bf(a0.w);
            v[4] = f2bf(a1.x); v[5] = f2bf(a1.y); v[6] = f2bf(a1.z); v[7] = f2bf(a1.w);
            *(u16x8*)&comb[srow][scol * 16] = v;
            u16x8 v2;
            v2[0] = f2bf(a2.x); v2[1] = f2bf(a2.y); v2[2] = f2bf(a2.z); v2[3] = f2bf(a2.w);
            v2[4] = f2bf(a3.x); v2[5] = f2bf(a3.y); v2[6] = f2bf(a3.z); v2[7] = f2bf(a3.w);
            *(u16x8*)&comb[srow][scol * 16 + 8] = v2;
        }
        __syncthreads();

        // ---- x-half MFMAs (independent of h_{t-1}; hides flag/data latency) ----
        f32x4 acc0a = {0.f, 0.f, 0.f, 0.f}, acc0b = {0.f, 0.f, 0.f, 0.f};
#pragma unroll
        for (int kk = 0; kk < 16; kk += 2) {
            bf16x8 a0 = *(const bf16x8*)&comb[n][kk * 32 + quad * 8];
            bf16x8 a1 = *(const bf16x8*)&comb[n][(kk + 1) * 32 + quad * 8];
            acc0a = __builtin_amdgcn_mfma_f32_16x16x32_bf16(a0, wfr[kk],     acc0a, 0, 0, 0);
            acc0b = __builtin_amdgcn_mfma_f32_16x16x32_bf16(a1, wfr[kk + 1], acc0b, 0, 0, 0);
        }

        // ---- wait for h_{t-1}: 16 relaxed flag polls (no buffer_inv), then bypass loads
        if (t > 0) {
            if (tid < 16) {
                unsigned int* fp = flags + ((size_t)(t - 1) * 8 + bgc) * 16 + tid;
                while (__hip_atomic_load(fp, __ATOMIC_RELAXED, __HIP_MEMORY_SCOPE_AGENT) == 0u) {
                    __builtin_amdgcn_s_sleep(1);
                }
            }
            __syncthreads();
            const unsigned long long* src = (const unsigned long long*)
                (hbuf + (size_t)((t - 1) & 1) * BATCH * HID + (size_t)(bgc * 16 + srow) * HID + scol * 16);
            unsigned long long v0 = __hip_atomic_load(src + 0, __ATOMIC_RELAXED, __HIP_MEMORY_SCOPE_AGENT);
            unsigned long long v1 = __hip_atomic_load(src + 1, __ATOMIC_RELAXED, __HIP_MEMORY_SCOPE_AGENT);
            unsigned long long v2 = __hip_atomic_load(src + 2, __ATOMIC_RELAXED, __HIP_MEMORY_SCOPE_AGENT);
            unsigned long long v3 = __hip_atomic_load(src + 3, __ATOMIC_RELAXED, __HIP_MEMORY_SCOPE_AGENT);
            unsigned long long* dst = (unsigned long long*)&comb[srow][512 + scol * 16];
            dst[0] = v0; dst[1] = v1; dst[2] = v2; dst[3] = v3;
        } else {
            uint4 z = {0u, 0u, 0u, 0u};
            *(uint4*)&comb[srow][512 + scol * 16]     = z;
            *(uint4*)&comb[srow][512 + scol * 16 + 8] = z;
        }
        __syncthreads();

        // ---- h-half MFMAs ----
        f32x4 acc1a = {0.f, 0.f, 0.f, 0.f}, acc1b = {0.f, 0.f, 0.f, 0.f};
#pragma unroll
        for (int kk = 16; kk < 32; kk += 2) {
            bf16x8 a0 = *(const bf16x8*)&comb[n][kk * 32 + quad * 8];
            bf16x8 a1 = *(const bf16x8*)&comb[n][(kk + 1) * 32 + quad * 8];
            acc1a = __builtin_amdgcn_mfma_f32_16x16x32_bf16(a0, wfr[kk],     acc1a, 0, 0, 0);
            acc1b = __builtin_amdgcn_mfma_f32_16x16x32_bf16(a1, wfr[kk + 1], acc1b, 0, 0, 0);
        }

        // ---- activations -> LDS gate exchange ----
#pragma unroll
        for (int r = 0; r < 4; ++r) {
            float v = acc0a[r] + acc0b[r] + acc1a[r] + acc1b[r] + bias;
            v = (gate == 2) ? tanhf_(v) : sigmoidf_(v);
            gatesl[gate][quad * 4 + r][uh * 16 + n] = v;
        }
        __syncthreads();

        // ---- LSTM cell; publish h_t ----
        {
            const int b = tid >> 5, u = tid & 31;
            float fv = gatesl[0][b][u], iv = gatesl[1][b][u];
            float gv = gatesl[2][b][u], ov = gatesl[3][b][u];
            float cn = fv * cl[b][u] + iv * gv;
            cl[b][u] = cn;
            float hv = ov * tanhf_(cn);
            const int bglob = bgc * 16 + b;
            const int uglob = cg * 32 + u;
            out[(size_t)t * BATCH * HID + (size_t)bglob * HID + uglob] = hv;
            if (t == T_STEPS - 1) {
                out[(size_t)T_STEPS * BATCH * HID + (size_t)bglob * HID + uglob] = hv;                 // hx
                out[(size_t)T_STEPS * BATCH * HID + BATCH * HID + (size_t)bglob * HID + uglob] = cn;   // cx
            }
            // pack pairs (u even gets u+1's value via shfl; adjacent lanes)
            unsigned int us  = (unsigned int)f2bf(hv);
            unsigned int us1 = (unsigned int)__shfl_down((int)us, 1);
            if ((u & 1) == 0) {
                unsigned int pv = us | (us1 << 16);
                unsigned int* hp = (unsigned int*)(hbuf + (size_t)(t & 1) * BATCH * HID
                                                   + (size_t)bglob * HID + uglob);
                __hip_atomic_store(hp, pv, __ATOMIC_RELAXED, __HIP_MEMORY_SCOPE_AGENT);
            }
        }
        // drain this wave's bypass stores (ack from LLC), then one flag store
        __builtin_amdgcn_s_waitcnt(0);
        __syncthreads();
        if (tid == 0) {
            __hip_atomic_store(flags + ((size_t)t * 8 + bgc) * 16 + cg, 1u,
                               __ATOMIC_RELAXED, __HIP_MEMORY_SCOPE_AGENT);
        }
    }
}

extern "C" void kernel_launch(void* const* d_in, const int* in_sizes, int n_in,
                              void* d_out, int out_size, void* d_ws, size_t ws_size,
                              hipStream_t stream) {
    (void)in_sizes; (void)n_in; (void)out_size;
    const float* x   = (const float*)d_in[0];
    const float* Wf  = (const float*)d_in[1];
    const float* bfv = (const float*)d_in[2];
    const float* Wi  = (const float*)d_in[3];
    const float* biv = (const float*)d_in[4];
    const float* Wg  = (const float*)d_in[5];
    const float* bgv = (const float*)d_in[6];
    const float* Wo  = (const float*)d_in[7];
    const float* bov = (const float*)d_in[8];
    float* out = (float*)d_out;

    unsigned char* ws = (unsigned char*)d_ws;
    unsigned int*   flags = (unsigned int*)ws;                        // 512*8*16*4 = 256 KB
    unsigned short* hbuf  = (unsigned short*)(ws + 262144);           // 2*128*512*2 = 256 KB
    unsigned short* xbf   = (unsigned short*)(ws + 524288);           // 64 MB (optional)

    size_t need = 524288 + (size_t)T_STEPS * BATCH * HID * 2;
    int use_xbf = (ws_size >= need) ? 1 : 0;

    hipMemsetAsync(flags, 0, 262144, stream);
    if (use_xbf) {
        int nelem = T_STEPS * BATCH * HID;
        cast_x_kernel<<<nelem / (256 * 8), 256, 0, stream>>>(x, xbf, nelem);
    }
    lstm_kernel<<<dim3(128), dim3(512), 0, stream>>>(
        x, xbf, Wf, bfv, Wi, biv, Wg, bgv, Wo, bov, out, flags, hbuf, use_xbf);
}

// Round 3
// 1936.210 us; speedup vs baseline: 6.4053x; 1.0178x over previous
//
#include <hip/hip_runtime.h>
#include <stdint.h>

#define T_STEPS 512
#define BATCH   128
#define HID     512
#define KTOT    1024

typedef __attribute__((ext_vector_type(8))) short          bf16x8;
typedef __attribute__((ext_vector_type(8))) unsigned short u16x8;
typedef __attribute__((ext_vector_type(4))) float          f32x4;

__device__ inline unsigned short f2bf(float f) {
    union { float f; unsigned u; } x; x.f = f;
    unsigned r = x.u + 0x7FFFu + ((x.u >> 16) & 1u);   // RNE
    return (unsigned short)(r >> 16);
}

__device__ inline float sigmoidf_(float x) { return 1.f / (1.f + __expf(-x)); }
__device__ inline float tanhf_(float x)    { float e = __expf(2.f * x); return 1.f - 2.f / (e + 1.f); }

// one-shot fp32 -> bf16 cast of the input sequence
__global__ void cast_x_kernel(const float* __restrict__ x, unsigned short* __restrict__ y, int n) {
    int i = (blockIdx.x * blockDim.x + threadIdx.x) * 8;
    if (i >= n) return;
    float4 a = *(const float4*)(x + i);
    float4 b = *(const float4*)(x + i + 4);
    u16x8 v;
    v[0] = f2bf(a.x); v[1] = f2bf(a.y); v[2] = f2bf(a.z); v[3] = f2bf(a.w);
    v[4] = f2bf(b.x); v[5] = f2bf(b.y); v[6] = f2bf(b.z); v[7] = f2bf(b.w);
    *(u16x8*)(y + i) = v;
}

// load 32B of x row-slice as packed bf16 (converting if source is fp32)
__device__ inline void load_x32(const float* xf, const unsigned short* xbf, int use_xbf,
                                size_t off, uint4& a, uint4& b) {
    if (use_xbf) {
        const uint4* p = (const uint4*)(xbf + off);
        a = p[0]; b = p[1];
    } else {
        const float4* p = (const float4*)(xf + off);
        float4 f0 = p[0], f1 = p[1], f2 = p[2], f3 = p[3];
        u16x8 v;
        v[0] = f2bf(f0.x); v[1] = f2bf(f0.y); v[2] = f2bf(f0.z); v[3] = f2bf(f0.w);
        v[4] = f2bf(f1.x); v[5] = f2bf(f1.y); v[6] = f2bf(f1.z); v[7] = f2bf(f1.w);
        a = *(uint4*)&v;
        u16x8 w;
        w[0] = f2bf(f2.x); w[1] = f2bf(f2.y); w[2] = f2bf(f2.z); w[3] = f2bf(f2.w);
        w[4] = f2bf(f3.x); w[5] = f2bf(f3.y); w[6] = f2bf(f3.z); w[7] = f2bf(f3.w);
        b = *(uint4*)&w;
    }
}

// Persistent LSTM. grid = 128 WGs (8 batch-groups x 16 col-groups), block = 512.
// Software-pipelined: x-prefetch (regs) and x-MFMA run one step ahead; the x-MFMA
// of step t+1 overlaps the h_t publish drain. 3 barriers/step, per-wave polling.
__global__ __launch_bounds__(512, 2) void lstm_kernel(
    const float* __restrict__ xf,
    const unsigned short* __restrict__ xbf,
    const float* __restrict__ Wf, const float* __restrict__ bfv,
    const float* __restrict__ Wi, const float* __restrict__ biv,
    const float* __restrict__ Wg, const float* __restrict__ bgv,
    const float* __restrict__ Wo, const float* __restrict__ bov,
    float* __restrict__ out,
    unsigned int* __restrict__ flags,      // [T][8][16] one dword per producer WG
    unsigned short* __restrict__ hbuf,     // [2][128][512] bf16, bypass-access only
    int use_xbf)
{
    // comb rows padded to 1048 shorts; x in cols 0..511, h in 512..1023.
    __shared__ __align__(16) unsigned short comb[16][1048];
    __shared__ float gatesl[4][16][33];

    const int tid  = threadIdx.x;
    const int bgc  = blockIdx.x >> 4;    // batch group 0..7
    const int cg   = blockIdx.x & 15;    // col group 0..15
    const int w    = tid >> 6;
    const int lane = tid & 63;
    const int gate = w & 3;              // 0=f 1=i 2=g 3=o
    const int uh   = w >> 2;
    const int n    = lane & 15;
    const int quad = lane >> 4;
    const int unit = cg * 32 + uh * 16 + n;

    const float* Wp = (gate == 0) ? Wf : (gate == 1) ? Wi : (gate == 2) ? Wg : Wo;
    const float* bp = (gate == 0) ? bfv : (gate == 1) ? biv : (gate == 2) ? bgv : bov;
    const float bias = bp[unit];

    // ---- preload W slice into registers as bf16 B-fragments (once) ----
    bf16x8 wfr[32];
    const float* wrow = Wp + (size_t)unit * KTOT;
#pragma unroll
    for (int kk = 0; kk < 32; ++kk) {
        const float4* p = (const float4*)(wrow + kk * 32 + quad * 8);
        float4 a = p[0], b = p[1];
        u16x8 v;
        v[0] = f2bf(a.x); v[1] = f2bf(a.y); v[2] = f2bf(a.z); v[3] = f2bf(a.w);
        v[4] = f2bf(b.x); v[5] = f2bf(b.y); v[6] = f2bf(b.z); v[7] = f2bf(b.w);
        wfr[kk] = (bf16x8)v;
    }

    const int srow = tid >> 5;   // staging row 0..15 (wave w owns rows 2w, 2w+1)
    const int scol = tid & 31;   // 16 shorts (32B) per thread per row

    // cell-thread mapping: this thread owns (bc, uc) forever; c lives in a register
    const int bc = srow, uc = scol;
    float creg = 0.f;
    const int bglob = bgc * 16 + bc;
    const int uglob = cg * 32 + uc;

    const size_t xstride = (size_t)HID;

    // ---- prologue: stage x_0, zero h region ----
    {
        uint4 a, b;
        load_x32(xf, xbf, use_xbf, ((size_t)(0 * BATCH + bgc * 16 + srow)) * xstride + scol * 16, a, b);
        *(uint4*)&comb[srow][scol * 16]     = a;
        *(uint4*)&comb[srow][scol * 16 + 8] = b;
        uint4 z = {0u, 0u, 0u, 0u};
        *(uint4*)&comb[srow][512 + scol * 16]     = z;
        *(uint4*)&comb[srow][512 + scol * 16 + 8] = z;
    }
    __syncthreads();

    // ---- x-MFMA for t=0 ----
    f32x4 axa = {0.f, 0.f, 0.f, 0.f}, axb = {0.f, 0.f, 0.f, 0.f};
#pragma unroll
    for (int kk = 0; kk < 16; kk += 2) {
        bf16x8 a0 = *(const bf16x8*)&comb[n][kk * 32 + quad * 8];
        bf16x8 a1 = *(const bf16x8*)&comb[n][(kk + 1) * 32 + quad * 8];
        axa = __builtin_amdgcn_mfma_f32_16x16x32_bf16(a0, wfr[kk],     axa, 0, 0, 0);
        axb = __builtin_amdgcn_mfma_f32_16x16x32_bf16(a1, wfr[kk + 1], axb, 0, 0, 0);
    }

    // ---- prefetch x_1 into registers ----
    uint4 pfa, pfb;
    load_x32(xf, xbf, use_xbf, ((size_t)(1 * BATCH + bgc * 16 + srow)) * xstride + scol * 16, pfa, pfb);

    for (int t = 0; t < T_STEPS; ++t) {
        // ---- per-wave poll for h_{t-1}, then wave-local load + LDS stage ----
        if (t > 0) {
            if (lane < 16) {
                unsigned int* fp = flags + ((size_t)(t - 1) * 8 + bgc) * 16 + lane;
                while (__hip_atomic_load(fp, __ATOMIC_RELAXED, __HIP_MEMORY_SCOPE_AGENT) == 0u) {}
            }
            const unsigned long long* src = (const unsigned long long*)
                (hbuf + (size_t)((t - 1) & 1) * BATCH * HID + (size_t)(bgc * 16 + srow) * HID + scol * 16);
            unsigned long long v0 = __hip_atomic_load(src + 0, __ATOMIC_RELAXED, __HIP_MEMORY_SCOPE_AGENT);
            unsigned long long v1 = __hip_atomic_load(src + 1, __ATOMIC_RELAXED, __HIP_MEMORY_SCOPE_AGENT);
            unsigned long long v2 = __hip_atomic_load(src + 2, __ATOMIC_RELAXED, __HIP_MEMORY_SCOPE_AGENT);
            unsigned long long v3 = __hip_atomic_load(src + 3, __ATOMIC_RELAXED, __HIP_MEMORY_SCOPE_AGENT);
            uint4 a, b;
            a.x = (unsigned)v0; a.y = (unsigned)(v0 >> 32);
            a.z = (unsigned)v1; a.w = (unsigned)(v1 >> 32);
            b.x = (unsigned)v2; b.y = (unsigned)(v2 >> 32);
            b.z = (unsigned)v3; b.w = (unsigned)(v3 >> 32);
            *(uint4*)&comb[srow][512 + scol * 16]     = a;
            *(uint4*)&comb[srow][512 + scol * 16 + 8] = b;
        }
        __syncthreads();   // h_{t-1} staged (t=0: zeros from prologue)

        // ---- h-MFMA accumulates onto the x-partials computed last iteration ----
#pragma unroll
        for (int kk = 16; kk < 32; kk += 2) {
            bf16x8 a0 = *(const bf16x8*)&comb[n][kk * 32 + quad * 8];
            bf16x8 a1 = *(const bf16x8*)&comb[n][(kk + 1) * 32 + quad * 8];
            axa = __builtin_amdgcn_mfma_f32_16x16x32_bf16(a0, wfr[kk],     axa, 0, 0, 0);
            axb = __builtin_amdgcn_mfma_f32_16x16x32_bf16(a1, wfr[kk + 1], axb, 0, 0, 0);
        }

        // ---- activations -> LDS gate exchange; also stage x_{t+1} from regs ----
#pragma unroll
        for (int r = 0; r < 4; ++r) {
            float v = axa[r] + axb[r] + bias;
            v = (gate == 2) ? tanhf_(v) : sigmoidf_(v);
            gatesl[gate][quad * 4 + r][uh * 16 + n] = v;
        }
        if (t + 1 < T_STEPS) {
            *(uint4*)&comb[srow][scol * 16]     = pfa;
            *(uint4*)&comb[srow][scol * 16 + 8] = pfb;
        }
        __syncthreads();   // gates + x_{t+1} staged

        // ---- LSTM cell (c in register); publish h_t; out store ----
        {
            float fv = gatesl[0][bc][uc], iv = gatesl[1][bc][uc];
            float gv = gatesl[2][bc][uc], ov = gatesl[3][bc][uc];
            float cn = fv * creg + iv * gv;
            creg = cn;
            float hv = ov * tanhf_(cn);
            // packed-pair bypass publish (issue first so the drain starts early)
            unsigned int us  = (unsigned int)f2bf(hv);
            unsigned int us1 = (unsigned int)__shfl_down((int)us, 1);
            if ((uc & 1) == 0) {
                unsigned int pv = us | (us1 << 16);
                unsigned int* hp = (unsigned int*)(hbuf + (size_t)(t & 1) * BATCH * HID
                                                   + (size_t)bglob * HID + uglob);
                __hip_atomic_store(hp, pv, __ATOMIC_RELAXED, __HIP_MEMORY_SCOPE_AGENT);
            }
            out[(size_t)t * BATCH * HID + (size_t)bglob * HID + uglob] = hv;
            if (t == T_STEPS - 1) {
                out[(size_t)T_STEPS * BATCH * HID + (size_t)bglob * HID + uglob] = hv;                 // hx
                out[(size_t)T_STEPS * BATCH * HID + BATCH * HID + (size_t)bglob * HID + uglob] = cn;   // cx
            }
        }

        // ---- x-MFMA for t+1 (overlaps the publish drain) ----
        if (t + 1 < T_STEPS) {
            axa = (f32x4){0.f, 0.f, 0.f, 0.f};
            axb = (f32x4){0.f, 0.f, 0.f, 0.f};
#pragma unroll
            for (int kk = 0; kk < 16; kk += 2) {
                bf16x8 a0 = *(const bf16x8*)&comb[n][kk * 32 + quad * 8];
                bf16x8 a1 = *(const bf16x8*)&comb[n][(kk + 1) * 32 + quad * 8];
                axa = __builtin_amdgcn_mfma_f32_16x16x32_bf16(a0, wfr[kk],     axa, 0, 0, 0);
                axb = __builtin_amdgcn_mfma_f32_16x16x32_bf16(a1, wfr[kk + 1], axb, 0, 0, 0);
            }
        }

        // ---- drain bypass stores, then one flag store; prefetch x_{t+2} ----
        __builtin_amdgcn_s_waitcnt(0);
        __syncthreads();   // all waves drained
        if (tid == 0) {
            __hip_atomic_store(flags + ((size_t)t * 8 + bgc) * 16 + cg, 1u,
                               __ATOMIC_RELAXED, __HIP_MEMORY_SCOPE_AGENT);
        }
        if (t + 2 < T_STEPS) {
            load_x32(xf, xbf, use_xbf,
                     ((size_t)((t + 2) * BATCH + bgc * 16 + srow)) * xstride + scol * 16, pfa, pfb);
        }
    }
}

extern "C" void kernel_launch(void* const* d_in, const int* in_sizes, int n_in,
                              void* d_out, int out_size, void* d_ws, size_t ws_size,
                              hipStream_t stream) {
    (void)in_sizes; (void)n_in; (void)out_size;
    const float* x   = (const float*)d_in[0];
    const float* Wf  = (const float*)d_in[1];
    const float* bfv = (const float*)d_in[2];
    const float* Wi  = (const float*)d_in[3];
    const float* biv = (const float*)d_in[4];
    const float* Wg  = (const float*)d_in[5];
    const float* bgv = (const float*)d_in[6];
    const float* Wo  = (const float*)d_in[7];
    const float* bov = (const float*)d_in[8];
    float* out = (float*)d_out;

    unsigned char* ws = (unsigned char*)d_ws;
    unsigned int*   flags = (unsigned int*)ws;                        // 512*8*16*4 = 256 KB
    unsigned short* hbuf  = (unsigned short*)(ws + 262144);           // 2*128*512*2 = 256 KB
    unsigned short* xbf   = (unsigned short*)(ws + 524288);           // 64 MB (optional)

    size_t need = 524288 + (size_t)T_STEPS * BATCH * HID * 2;
    int use_xbf = (ws_size >= need) ? 1 : 0;

    hipMemsetAsync(flags, 0, 262144, stream);
    if (use_xbf) {
        int nelem = T_STEPS * BATCH * HID;
        cast_x_kernel<<<nelem / (256 * 8), 256, 0, stream>>>(x, xbf, nelem);
    }
    lstm_kernel<<<dim3(128), dim3(512), 0, stream>>>(
        x, xbf, Wf, bfv, Wi, biv, Wg, bgv, Wo, bov, out, flags, hbuf, use_xbf);
}